// Round 5
// baseline (593.381 us; speedup 1.0000x reference)
//
#include <hip/hip_runtime.h>
#include <hip/hip_bf16.h>
#include <cstdint>
#include <type_traits>

// H=8, T=2048, E=512. Inputs/outputs FLOAT32; bf16/f32 intermediates.
// All GEMMs NT: C[m][n] = sum_k A[m][k]*B[n][k]  (A:[MxK] lda, B:[NxK] ldb).
// MFMA core: 128x128 tile, 4 waves, BK=32, mfma_f32_16x16x32_bf16.
// f32 operands are register-prefetch software-pipelined (load k+1 during MFMA k);
// bf16 operands stage via global_load_lds width-16.
// Split-K via blockIdx.z = zh*NZK + zk (zh = head, zk = K-slice, atomic f32 C).

#define HH 8
#define TT 2048
#define EE 512
#define HT (HH * TT)

typedef __bf16 bf16_t;
typedef __attribute__((ext_vector_type(8))) __bf16 bf16x8;
typedef __attribute__((ext_vector_type(4))) float f32x4;

// ---------- staging helpers ----------
__device__ __forceinline__ void stage_lds(const bf16_t* __restrict__ g, bf16_t* l) {
  __builtin_amdgcn_global_load_lds(
      (const __attribute__((address_space(1))) unsigned int*)g,
      (__attribute__((address_space(3))) unsigned int*)l, 16, 0, 0);
}

struct PF { float4 lo, hi; };
__device__ __forceinline__ void pf_load(const float* __restrict__ g, PF& r) {
  r.lo = ((const float4*)g)[0];
  r.hi = ((const float4*)g)[1];
}
__device__ __forceinline__ void pf_store(bf16_t* l, const PF& r) {
  bf16x8 o;
  o[0] = (__bf16)r.lo.x; o[1] = (__bf16)r.lo.y; o[2] = (__bf16)r.lo.z; o[3] = (__bf16)r.lo.w;
  o[4] = (__bf16)r.hi.x; o[5] = (__bf16)r.hi.y; o[6] = (__bf16)r.hi.z; o[7] = (__bf16)r.hi.w;
  *(bf16x8*)l = o;
}

template <typename CT, bool ATOMIC>
__device__ __forceinline__ void store_c(CT* p, float v) {
  if constexpr (ATOMIC) atomicAdd((float*)p, v);
  else *p = (CT)v;
}

// ---------- MFMA NT GEMM ----------
// grid (M/128, N/128, ZH*NZK). Offsets: A += zh*sAh + zk*sAk, B += zh*sBh + zk*sBk,
// C += zh*sCh. bias_m/bias_n offset by zh*sBMh/sBNh, applied only when zk==0.
template <typename AT, typename BT, typename CT, bool ATOMIC, int NZK>
__global__ __launch_bounds__(256) void mfma_gemm_nt(
    const AT* __restrict__ A, const BT* __restrict__ B, CT* __restrict__ C,
    const float* __restrict__ bias_m, const float* __restrict__ bias_n,
    int K, int lda, int ldb, int ldc,
    int64_t sAh, int64_t sAk, int64_t sBh, int64_t sBk, int64_t sCh,
    int64_t sBMh, int64_t sBNh) {
  constexpr bool A_F32 = std::is_same<AT, float>::value;
  constexpr bool B_F32 = std::is_same<BT, float>::value;
  const int zh = blockIdx.z / NZK;
  const int zk = blockIdx.z % NZK;
  A += zh * sAh + zk * sAk;
  B += zh * sBh + zk * sBk;
  C += zh * sCh;
  const bool do_bias = (zk == 0);
  if (bias_m) bias_m += zh * sBMh;
  if (bias_n) bias_n += zh * sBNh;

  const int m0 = blockIdx.x * 128;
  const int n0 = blockIdx.y * 128;
  const int tid = threadIdx.x;

  __shared__ bf16_t sAb[128 * 32];  // 8 KB
  __shared__ bf16_t sBb[128 * 32];  // 8 KB

  const int srow = tid >> 2;
  const int scol = (tid & 3) * 8;
  const AT* a0 = A + (int64_t)(m0 + srow) * lda + scol;
  const AT* a1 = a0 + (int64_t)64 * lda;
  const BT* b0 = B + (int64_t)(n0 + srow) * ldb + scol;
  const BT* b1 = b0 + (int64_t)64 * ldb;
  bf16_t* la0 = sAb + tid * 8;
  bf16_t* la1 = sAb + 2048 + tid * 8;
  bf16_t* lb0 = sBb + tid * 8;
  bf16_t* lb1 = sBb + 2048 + tid * 8;

  const int wave = tid >> 6;
  const int lane = tid & 63;
  const int wm = (wave >> 1) * 64;
  const int wn = (wave & 1) * 64;
  const int fr = lane & 15;  // frag row (m for A, n for B); output col
  const int qd = lane >> 4;  // quad; output rows qd*4..+3

  f32x4 acc[4][4];
#pragma unroll
  for (int i = 0; i < 4; i++)
#pragma unroll
    for (int j = 0; j < 4; j++) acc[i][j] = (f32x4){0.f, 0.f, 0.f, 0.f};

  PF pa0, pa1, pb0, pb1;
  if constexpr (A_F32) { pf_load((const float*)a0, pa0); pf_load((const float*)a1, pa1); }
  if constexpr (B_F32) { pf_load((const float*)b0, pb0); pf_load((const float*)b1, pb1); }

  for (int kt = 0; kt < K; kt += 32) {
    __syncthreads();  // previous tile's frag reads done
    if constexpr (A_F32) {
      pf_store(la0, pa0);
      pf_store(la1, pa1);
    } else {
      stage_lds((const bf16_t*)a0 + kt, la0);
      stage_lds((const bf16_t*)a1 + kt, la1);
    }
    if constexpr (B_F32) {
      pf_store(lb0, pb0);
      pf_store(lb1, pb1);
    } else {
      stage_lds((const bf16_t*)b0 + kt, lb0);
      stage_lds((const bf16_t*)b1 + kt, lb1);
    }
    // software-pipeline the f32 path: next tile's loads fly during MFMA phase
    if (kt + 32 < K) {
      if constexpr (A_F32) {
        pf_load((const float*)a0 + kt + 32, pa0);
        pf_load((const float*)a1 + kt + 32, pa1);
      }
      if constexpr (B_F32) {
        pf_load((const float*)b0 + kt + 32, pb0);
        pf_load((const float*)b1 + kt + 32, pb1);
      }
    }
    __syncthreads();  // staging visible

    bf16x8 af[4], bfr[4];
#pragma unroll
    for (int i = 0; i < 4; i++)
      af[i] = *(const bf16x8*)&sAb[(wm + i * 16 + fr) * 32 + qd * 8];
#pragma unroll
    for (int j = 0; j < 4; j++)
      bfr[j] = *(const bf16x8*)&sBb[(wn + j * 16 + fr) * 32 + qd * 8];
#pragma unroll
    for (int i = 0; i < 4; i++)
#pragma unroll
      for (int j = 0; j < 4; j++)
        acc[i][j] = __builtin_amdgcn_mfma_f32_16x16x32_bf16(af[i], bfr[j], acc[i][j], 0, 0, 0);
  }

#pragma unroll
  for (int i = 0; i < 4; i++) {
    const int row0 = m0 + wm + i * 16 + qd * 4;
#pragma unroll
    for (int j = 0; j < 4; j++) {
      const int col = n0 + wn + j * 16 + fr;
      const float bn = (bias_n && do_bias) ? bias_n[col] : 0.f;
#pragma unroll
      for (int r = 0; r < 4; r++) {
        const float bm = (bias_m && do_bias) ? bias_m[row0 + r] : 0.f;
        store_c<CT, ATOMIC>(&C[(int64_t)(row0 + r) * ldc + col], acc[i][j][r] + bn + bm);
      }
    }
  }
}

// ---------- f32 -> bf16 convert (n multiple of 2048) ----------
__global__ __launch_bounds__(256) void cvt_bf16(const float* __restrict__ s,
                                                bf16_t* __restrict__ d) {
  const int64_t i = ((int64_t)blockIdx.x * 256 + threadIdx.x) * 8;
  float4 u = ((const float4*)(s + i))[0];
  float4 v = ((const float4*)(s + i))[1];
  bf16x8 o;
  o[0] = (__bf16)u.x; o[1] = (__bf16)u.y; o[2] = (__bf16)u.z; o[3] = (__bf16)u.w;
  o[4] = (__bf16)v.x; o[5] = (__bf16)v.y; o[6] = (__bf16)v.z; o[7] = (__bf16)v.w;
  *(bf16x8*)(d + i) = o;
}

// ---------- in-place row softmax (rows of length T), 1/sqrt(T) pre-scale ----------
__global__ __launch_bounds__(256) void softmax_rows(bf16_t* __restrict__ S) {
  const float scale = 0.022097086912079608f;  // 1/sqrt(2048)
  bf16_t* p = S + (int64_t)blockIdx.x * TT;
  const int tid = threadIdx.x;
  bf16x8 rv = *(const bf16x8*)(p + tid * 8);
  float v[8];
  float mx = -1e30f;
#pragma unroll
  for (int i = 0; i < 8; i++) {
    v[i] = (float)rv[i] * scale;
    mx = fmaxf(mx, v[i]);
  }
#pragma unroll
  for (int o = 32; o > 0; o >>= 1) mx = fmaxf(mx, __shfl_xor(mx, o));
  __shared__ float redm[4], reds[4];
  if ((tid & 63) == 0) redm[tid >> 6] = mx;
  __syncthreads();
  mx = fmaxf(fmaxf(redm[0], redm[1]), fmaxf(redm[2], redm[3]));
  float sum = 0.f;
#pragma unroll
  for (int i = 0; i < 8; i++) {
    v[i] = __expf(v[i] - mx);
    sum += v[i];
  }
#pragma unroll
  for (int o = 32; o > 0; o >>= 1) sum += __shfl_xor(sum, o);
  if ((tid & 63) == 0) reds[tid >> 6] = sum;
  __syncthreads();
  sum = reds[0] + reds[1] + reds[2] + reds[3];
  const float inv = 1.0f / sum;
  bf16x8 ov;
#pragma unroll
  for (int i = 0; i < 8; i++) ov[i] = (__bf16)(v[i] * inv);
  *(bf16x8*)(p + tid * 8) = ov;
}

// ---------- out = LN(fin + bf[t] + z), eps=1e-4, population var ----------
__global__ __launch_bounds__(256) void ln_res(const float* __restrict__ F,
                                              const float* __restrict__ Z,
                                              const float* __restrict__ BF,
                                              float* __restrict__ O) {
  const int row = blockIdx.x;
  const float* f = F + (int64_t)row * EE;
  const float* z = Z + (int64_t)row * EE;
  float* o = O + (int64_t)row * EE;
  const float bft = BF[row];
  const int tid = threadIdx.x;
  const float a = f[tid] + bft + z[tid];
  const float b = f[tid + 256] + bft + z[tid + 256];
  float s = a + b, ss = a * a + b * b;
#pragma unroll
  for (int w = 32; w > 0; w >>= 1) {
    s += __shfl_xor(s, w);
    ss += __shfl_xor(ss, w);
  }
  __shared__ float rs[4], rss[4];
  if ((tid & 63) == 0) {
    rs[tid >> 6] = s;
    rss[tid >> 6] = ss;
  }
  __syncthreads();
  s = rs[0] + rs[1] + rs[2] + rs[3];
  ss = rss[0] + rss[1] + rss[2] + rss[3];
  const float mean = s * (1.0f / EE);
  const float var = ss * (1.0f / EE) - mean * mean;
  const float inv = rsqrtf(var + 1e-4f);
  o[tid] = (a - mean) * inv;
  o[tid + 256] = (b - mean) * inv;
}

extern "C" void kernel_launch(void* const* d_in, const int* in_sizes, int n_in,
                              void* d_out, int out_size, void* d_ws, size_t ws_size,
                              hipStream_t stream) {
  const float* x = (const float*)d_in[0];
  const float* y = (const float*)d_in[1];
  const float* z = (const float*)d_in[2];
  const float* Wq = (const float*)d_in[3];
  const float* bq = (const float*)d_in[4];
  const float* Wk = (const float*)d_in[5];
  const float* bk = (const float*)d_in[6];
  const float* Wv = (const float*)d_in[7];
  const float* bv = (const float*)d_in[8];
  const float* Wf = (const float*)d_in[9];
  const float* bfb = (const float*)d_in[10];
  float* out = (float*)d_out;

  const size_t MB = 1ull << 20;
  char* p = (char*)d_ws;
  const int64_t nTE = (int64_t)TT * EE;      // 1M elems
  const int64_t nW = (int64_t)HH * EE * EE;  // 2M elems

  // shared conversions
  bf16_t* xb = (bf16_t*)(p + 0 * MB);
  bf16_t* yb = (bf16_t*)(p + 2 * MB);
  bf16_t* zb = (bf16_t*)(p + 4 * MB);
  bf16_t* Wqb = (bf16_t*)(p + 6 * MB);
  bf16_t* Wkb = (bf16_t*)(p + 10 * MB);
  bf16_t* Wvb = (bf16_t*)(p + 14 * MB);
  cvt_bf16<<<nTE / 2048, 256, 0, stream>>>(x, xb);
  cvt_bf16<<<nTE / 2048, 256, 0, stream>>>(y, yb);
  cvt_bf16<<<nTE / 2048, 256, 0, stream>>>(z, zb);
  cvt_bf16<<<nW / 2048, 256, 0, stream>>>(Wq, Wqb);
  cvt_bf16<<<nW / 2048, 256, 0, stream>>>(Wk, Wkb);
  cvt_bf16<<<nW / 2048, 256, 0, stream>>>(Wv, Wvb);

  if (ws_size >= 167 * MB) {
    // ---- Tier A (166 MB): head-batched, f32 hoT, split-K AV + final ----
    bf16_t* q = (bf16_t*)(p + 18 * MB);    // [8][T][E]
    bf16_t* k = (bf16_t*)(p + 34 * MB);    // [8][T][E]
    bf16_t* vT = (bf16_t*)(p + 50 * MB);   // [8][E][T]
    bf16_t* att = (bf16_t*)(p + 66 * MB);  // [8][T][T]
    float* hoT = (float*)(p + 130 * MB);   // [E][H*T] f32 (32 MB)
    float* fin = (float*)(p + 162 * MB);   // [T][E] f32

    mfma_gemm_nt<bf16_t, bf16_t, bf16_t, false, 1><<<dim3(16, 4, 8), 256, 0, stream>>>(
        xb, Wqb, q, nullptr, bq, EE, EE, EE, EE, 0, 0, (int64_t)EE * EE, 0,
        (int64_t)TT * EE, 0, EE);
    mfma_gemm_nt<bf16_t, bf16_t, bf16_t, false, 1><<<dim3(16, 4, 8), 256, 0, stream>>>(
        yb, Wkb, k, nullptr, bk, EE, EE, EE, EE, 0, 0, (int64_t)EE * EE, 0,
        (int64_t)TT * EE, 0, EE);
    mfma_gemm_nt<bf16_t, bf16_t, bf16_t, false, 1><<<dim3(4, 16, 8), 256, 0, stream>>>(
        Wvb, zb, vT, bv, nullptr, EE, EE, EE, TT, (int64_t)EE * EE, 0, 0, 0,
        (int64_t)EE * TT, EE, 0);
    mfma_gemm_nt<bf16_t, bf16_t, bf16_t, false, 1><<<dim3(16, 16, 8), 256, 0, stream>>>(
        q, k, att, nullptr, nullptr, EE, EE, EE, TT, (int64_t)TT * EE, 0,
        (int64_t)TT * EE, 0, (int64_t)TT * TT, 0, 0);
    softmax_rows<<<HH * TT, 256, 0, stream>>>(att);
    // AV: hoT[f][h*T+s] = sum_t vT[h][f][t] att[h][s][t], split-K NZK=2 (K=1024/slice)
    hipMemsetAsync(hoT, 0, (size_t)EE * HT * 4, stream);
    mfma_gemm_nt<bf16_t, bf16_t, float, true, 2><<<dim3(4, 16, 16), 256, 0, stream>>>(
        vT, att, hoT, nullptr, nullptr, 1024, TT, TT, HT, (int64_t)EE * TT, 1024,
        (int64_t)TT * TT, 1024, TT, 0, 0);
    // final: fin[t][e] = Wf[t][:] . hoT[e][:], split-K NZK=16 (K=1024/slice)
    hipMemsetAsync(fin, 0, (size_t)TT * EE * 4, stream);
    mfma_gemm_nt<float, float, float, true, 16><<<dim3(16, 4, 16), 256, 0, stream>>>(
        Wf, hoT, fin, nullptr, nullptr, 1024, HT, HT, EE, 0, 1024, 0, 1024, 0, 0, 0);
    ln_res<<<TT, 256, 0, stream>>>(fin, z, bfb, out);
  } else if (ws_size >= 151 * MB) {
    // ---- Tier B (150 MB): round-4 FULL + upgraded final ----
    bf16_t* q = (bf16_t*)(p + 18 * MB);
    bf16_t* k = (bf16_t*)(p + 34 * MB);
    bf16_t* vT = (bf16_t*)(p + 50 * MB);
    bf16_t* att = (bf16_t*)(p + 66 * MB);
    bf16_t* hoT = (bf16_t*)(p + 130 * MB);  // [E][H*T] bf16
    float* fin = (float*)(p + 146 * MB);

    mfma_gemm_nt<bf16_t, bf16_t, bf16_t, false, 1><<<dim3(16, 4, 8), 256, 0, stream>>>(
        xb, Wqb, q, nullptr, bq, EE, EE, EE, EE, 0, 0, (int64_t)EE * EE, 0,
        (int64_t)TT * EE, 0, EE);
    mfma_gemm_nt<bf16_t, bf16_t, bf16_t, false, 1><<<dim3(16, 4, 8), 256, 0, stream>>>(
        yb, Wkb, k, nullptr, bk, EE, EE, EE, EE, 0, 0, (int64_t)EE * EE, 0,
        (int64_t)TT * EE, 0, EE);
    mfma_gemm_nt<bf16_t, bf16_t, bf16_t, false, 1><<<dim3(4, 16, 8), 256, 0, stream>>>(
        Wvb, zb, vT, bv, nullptr, EE, EE, EE, TT, (int64_t)EE * EE, 0, 0, 0,
        (int64_t)EE * TT, EE, 0);
    mfma_gemm_nt<bf16_t, bf16_t, bf16_t, false, 1><<<dim3(16, 16, 8), 256, 0, stream>>>(
        q, k, att, nullptr, nullptr, EE, EE, EE, TT, (int64_t)TT * EE, 0,
        (int64_t)TT * EE, 0, (int64_t)TT * TT, 0, 0);
    softmax_rows<<<HH * TT, 256, 0, stream>>>(att);
    mfma_gemm_nt<bf16_t, bf16_t, bf16_t, false, 1><<<dim3(4, 16, 8), 256, 0, stream>>>(
        vT, att, hoT, nullptr, nullptr, TT, TT, TT, HT, (int64_t)EE * TT, 0,
        (int64_t)TT * TT, 0, TT, 0, 0);
    hipMemsetAsync(fin, 0, (size_t)TT * EE * 4, stream);
    mfma_gemm_nt<float, bf16_t, float, true, 16><<<dim3(16, 4, 16), 256, 0, stream>>>(
        Wf, hoT, fin, nullptr, nullptr, 1024, HT, HT, EE, 0, 1024, 0, 1024, 0, 0, 0);
    ln_res<<<TT, 256, 0, stream>>>(fin, z, bfb, out);
  } else {
    // ---- Tier C (52 MB): per-head LEAN + upgraded final ----
    bf16_t* qh = (bf16_t*)(p + 18 * MB);
    bf16_t* kh = (bf16_t*)(p + 20 * MB);
    bf16_t* vTh = (bf16_t*)(p + 22 * MB);
    bf16_t* att = (bf16_t*)(p + 24 * MB);
    bf16_t* hoT = (bf16_t*)(p + 32 * MB);
    float* fin = (float*)(p + 48 * MB);

    for (int h = 0; h < HH; h++) {
      const bf16_t* Wq_h = Wqb + (int64_t)h * EE * EE;
      const bf16_t* Wk_h = Wkb + (int64_t)h * EE * EE;
      const bf16_t* Wv_h = Wvb + (int64_t)h * EE * EE;
      mfma_gemm_nt<bf16_t, bf16_t, bf16_t, false, 1><<<dim3(16, 4, 1), 256, 0, stream>>>(
          xb, Wq_h, qh, nullptr, bq + h * EE, EE, EE, EE, EE, 0, 0, 0, 0, 0, 0, 0);
      mfma_gemm_nt<bf16_t, bf16_t, bf16_t, false, 1><<<dim3(16, 4, 1), 256, 0, stream>>>(
          yb, Wk_h, kh, nullptr, bk + h * EE, EE, EE, EE, EE, 0, 0, 0, 0, 0, 0, 0);
      mfma_gemm_nt<bf16_t, bf16_t, bf16_t, false, 1><<<dim3(4, 16, 1), 256, 0, stream>>>(
          Wv_h, zb, vTh, bv + h * EE, nullptr, EE, EE, EE, TT, 0, 0, 0, 0, 0, 0, 0);
      mfma_gemm_nt<bf16_t, bf16_t, bf16_t, false, 1><<<dim3(16, 16, 1), 256, 0, stream>>>(
          qh, kh, att, nullptr, nullptr, EE, EE, EE, TT, 0, 0, 0, 0, 0, 0, 0);
      softmax_rows<<<TT, 256, 0, stream>>>(att);
      mfma_gemm_nt<bf16_t, bf16_t, bf16_t, false, 1><<<dim3(4, 16, 1), 256, 0, stream>>>(
          vTh, att, hoT + (int64_t)h * TT, nullptr, nullptr, TT, TT, TT, HT, 0, 0, 0, 0, 0,
          0, 0);
    }
    hipMemsetAsync(fin, 0, (size_t)TT * EE * 4, stream);
    mfma_gemm_nt<float, bf16_t, float, true, 16><<<dim3(16, 4, 16), 256, 0, stream>>>(
        Wf, hoT, fin, nullptr, nullptr, 1024, HT, HT, EE, 0, 1024, 0, 1024, 0, 0, 0);
    ln_res<<<TT, 256, 0, stream>>>(fin, z, bfb, out);
  }
}

// Round 6
// 570.863 us; speedup vs baseline: 1.0394x; 1.0394x over previous
//
#include <hip/hip_runtime.h>
#include <hip/hip_bf16.h>
#include <cstdint>

// H=8, T=2048, E=512. Inputs/outputs FLOAT32; all GEMM operands bf16.
// All GEMMs NT: C[m][n] = sum_k A[m][k]*B[n][k]  (A:[MxK] lda, B:[NxK] ldb).
// MFMA core: 128x128 tile, 4 waves, BK=32, mfma_f32_16x16x32_bf16,
// global_load_lds width-16 staging (m97 structure). NO atomics anywhere:
// the final GEMM uses split-K=4 into 4 separate f32 partial planes, reduced in ln_res.
//
// Workspace (peak 146 MB, proven ws_size >= 151 MB):
//   0   xb 2 | 2 yb 2 | 4 zb 2 | 6 Wqb 4 | 10 Wkb 4 | 14 Wvb 4
//   18  q 16  (aliased by fin4 16 MB after scores GEMM)
//   34  k 16 | 50 vT 16
//   66  att 64  (aliased by Wfb 64 MB after AV GEMM)
//   130 hoT 16

#define HH 8
#define TT 2048
#define EE 512
#define HT (HH * TT)

typedef __bf16 bf16_t;
typedef __attribute__((ext_vector_type(8))) __bf16 bf16x8;
typedef __attribute__((ext_vector_type(4))) float f32x4;

__device__ __forceinline__ void stage_lds(const bf16_t* __restrict__ g, bf16_t* l) {
  __builtin_amdgcn_global_load_lds(
      (const __attribute__((address_space(1))) unsigned int*)g,
      (__attribute__((address_space(3))) unsigned int*)l, 16, 0, 0);
}

// ---------- MFMA NT GEMM (all-bf16 operands) ----------
// grid (M/128, N/128, Z). Per-z offsets (elements): A += z*sAz, B += z*sBz,
// C += z*sCz, bias_m += z*sBMz, bias_n += z*sBNz.
template <typename CT>
__global__ __launch_bounds__(256) void mfma_gemm_nt(
    const bf16_t* __restrict__ A, const bf16_t* __restrict__ B, CT* __restrict__ C,
    const float* __restrict__ bias_m, const float* __restrict__ bias_n,
    int K, int lda, int ldb, int ldc,
    int64_t sAz, int64_t sBz, int64_t sCz, int64_t sBMz, int64_t sBNz) {
  const int z = blockIdx.z;
  A += z * sAz;
  B += z * sBz;
  C += z * sCz;
  if (bias_m) bias_m += z * sBMz;
  if (bias_n) bias_n += z * sBNz;

  const int m0 = blockIdx.x * 128;
  const int n0 = blockIdx.y * 128;
  const int tid = threadIdx.x;

  __shared__ bf16_t sAb[128 * 32];  // 8 KB
  __shared__ bf16_t sBb[128 * 32];  // 8 KB

  const int srow = tid >> 2;
  const int scol = (tid & 3) * 8;
  const bf16_t* a0 = A + (int64_t)(m0 + srow) * lda + scol;
  const bf16_t* a1 = a0 + (int64_t)64 * lda;
  const bf16_t* b0 = B + (int64_t)(n0 + srow) * ldb + scol;
  const bf16_t* b1 = b0 + (int64_t)64 * ldb;
  bf16_t* la0 = sAb + tid * 8;
  bf16_t* la1 = sAb + 2048 + tid * 8;
  bf16_t* lb0 = sBb + tid * 8;
  bf16_t* lb1 = sBb + 2048 + tid * 8;

  const int wave = tid >> 6;
  const int lane = tid & 63;
  const int wm = (wave >> 1) * 64;
  const int wn = (wave & 1) * 64;
  const int fr = lane & 15;  // frag row (m for A, n for B); output col
  const int qd = lane >> 4;  // quad; output rows qd*4..+3

  f32x4 acc[4][4];
#pragma unroll
  for (int i = 0; i < 4; i++)
#pragma unroll
    for (int j = 0; j < 4; j++) acc[i][j] = (f32x4){0.f, 0.f, 0.f, 0.f};

  for (int kt = 0; kt < K; kt += 32) {
    __syncthreads();  // previous tile's frag reads done
    stage_lds(a0 + kt, la0);
    stage_lds(a1 + kt, la1);
    stage_lds(b0 + kt, lb0);
    stage_lds(b1 + kt, lb1);
    __syncthreads();  // staging visible

    bf16x8 af[4], bfr[4];
#pragma unroll
    for (int i = 0; i < 4; i++)
      af[i] = *(const bf16x8*)&sAb[(wm + i * 16 + fr) * 32 + qd * 8];
#pragma unroll
    for (int j = 0; j < 4; j++)
      bfr[j] = *(const bf16x8*)&sBb[(wn + j * 16 + fr) * 32 + qd * 8];
#pragma unroll
    for (int i = 0; i < 4; i++)
#pragma unroll
      for (int j = 0; j < 4; j++)
        acc[i][j] = __builtin_amdgcn_mfma_f32_16x16x32_bf16(af[i], bfr[j], acc[i][j], 0, 0, 0);
  }

#pragma unroll
  for (int i = 0; i < 4; i++) {
    const int row0 = m0 + wm + i * 16 + qd * 4;
#pragma unroll
    for (int j = 0; j < 4; j++) {
      const int col = n0 + wn + j * 16 + fr;
      const float bn = bias_n ? bias_n[col] : 0.f;
#pragma unroll
      for (int r = 0; r < 4; r++) {
        const float bm = bias_m ? bias_m[row0 + r] : 0.f;
        C[(int64_t)(row0 + r) * ldc + col] = (CT)(acc[i][j][r] + bn + bm);
      }
    }
  }
}

// ---------- f32 -> bf16 convert (n multiple of 2048) ----------
__global__ __launch_bounds__(256) void cvt_bf16(const float* __restrict__ s,
                                                bf16_t* __restrict__ d) {
  const int64_t i = ((int64_t)blockIdx.x * 256 + threadIdx.x) * 8;
  float4 u = ((const float4*)(s + i))[0];
  float4 v = ((const float4*)(s + i))[1];
  bf16x8 o;
  o[0] = (__bf16)u.x; o[1] = (__bf16)u.y; o[2] = (__bf16)u.z; o[3] = (__bf16)u.w;
  o[4] = (__bf16)v.x; o[5] = (__bf16)v.y; o[6] = (__bf16)v.z; o[7] = (__bf16)v.w;
  *(bf16x8*)(d + i) = o;
}

// ---------- in-place row softmax (rows of length T), 1/sqrt(T) pre-scale ----------
__global__ __launch_bounds__(256) void softmax_rows(bf16_t* __restrict__ S) {
  const float scale = 0.022097086912079608f;  // 1/sqrt(2048)
  bf16_t* p = S + (int64_t)blockIdx.x * TT;
  const int tid = threadIdx.x;
  bf16x8 rv = *(const bf16x8*)(p + tid * 8);
  float v[8];
  float mx = -1e30f;
#pragma unroll
  for (int i = 0; i < 8; i++) {
    v[i] = (float)rv[i] * scale;
    mx = fmaxf(mx, v[i]);
  }
#pragma unroll
  for (int o = 32; o > 0; o >>= 1) mx = fmaxf(mx, __shfl_xor(mx, o));
  __shared__ float redm[4], reds[4];
  if ((tid & 63) == 0) redm[tid >> 6] = mx;
  __syncthreads();
  mx = fmaxf(fmaxf(redm[0], redm[1]), fmaxf(redm[2], redm[3]));
  float sum = 0.f;
#pragma unroll
  for (int i = 0; i < 8; i++) {
    v[i] = __expf(v[i] - mx);
    sum += v[i];
  }
#pragma unroll
  for (int o = 32; o > 0; o >>= 1) sum += __shfl_xor(sum, o);
  if ((tid & 63) == 0) reds[tid >> 6] = sum;
  __syncthreads();
  sum = reds[0] + reds[1] + reds[2] + reds[3];
  const float inv = 1.0f / sum;
  bf16x8 ov;
#pragma unroll
  for (int i = 0; i < 8; i++) ov[i] = (__bf16)(v[i] * inv);
  *(bf16x8*)(p + tid * 8) = ov;
}

// ---------- out = LN(sum_{zk} fin4[zk] + bf[t] + z), eps=1e-4, population var ----------
__global__ __launch_bounds__(256) void ln_res4(const float* __restrict__ F,
                                               const float* __restrict__ Z,
                                               const float* __restrict__ BF,
                                               float* __restrict__ O) {
  const int row = blockIdx.x;
  const int64_t off = (int64_t)row * EE;
  const int64_t plane = (int64_t)TT * EE;
  const float* z = Z + off;
  float* o = O + off;
  const float bft = BF[row];
  const int tid = threadIdx.x;
  float a = bft + z[tid];
  float b = bft + z[tid + 256];
#pragma unroll
  for (int zk = 0; zk < 4; zk++) {
    const float* f = F + zk * plane + off;
    a += f[tid];
    b += f[tid + 256];
  }
  float s = a + b, ss = a * a + b * b;
#pragma unroll
  for (int w = 32; w > 0; w >>= 1) {
    s += __shfl_xor(s, w);
    ss += __shfl_xor(ss, w);
  }
  __shared__ float rs[4], rss[4];
  if ((tid & 63) == 0) {
    rs[tid >> 6] = s;
    rss[tid >> 6] = ss;
  }
  __syncthreads();
  s = rs[0] + rs[1] + rs[2] + rs[3];
  ss = rss[0] + rss[1] + rss[2] + rss[3];
  const float mean = s * (1.0f / EE);
  const float var = ss * (1.0f / EE) - mean * mean;
  const float inv = rsqrtf(var + 1e-4f);
  o[tid] = (a - mean) * inv;
  o[tid + 256] = (b - mean) * inv;
}

extern "C" void kernel_launch(void* const* d_in, const int* in_sizes, int n_in,
                              void* d_out, int out_size, void* d_ws, size_t ws_size,
                              hipStream_t stream) {
  const float* x = (const float*)d_in[0];
  const float* y = (const float*)d_in[1];
  const float* z = (const float*)d_in[2];
  const float* Wq = (const float*)d_in[3];
  const float* bq = (const float*)d_in[4];
  const float* Wk = (const float*)d_in[5];
  const float* bk = (const float*)d_in[6];
  const float* Wv = (const float*)d_in[7];
  const float* bv = (const float*)d_in[8];
  const float* Wf = (const float*)d_in[9];
  const float* bfb = (const float*)d_in[10];
  float* out = (float*)d_out;

  const size_t MB = 1ull << 20;
  char* p = (char*)d_ws;
  const int64_t nTE = (int64_t)TT * EE;      // 1M elems
  const int64_t nW = (int64_t)HH * EE * EE;  // 2M elems
  const int64_t nWf = (int64_t)TT * HT;      // 32M elems

  bf16_t* xb = (bf16_t*)(p + 0 * MB);
  bf16_t* yb = (bf16_t*)(p + 2 * MB);
  bf16_t* zb = (bf16_t*)(p + 4 * MB);
  bf16_t* Wqb = (bf16_t*)(p + 6 * MB);
  bf16_t* Wkb = (bf16_t*)(p + 10 * MB);
  bf16_t* Wvb = (bf16_t*)(p + 14 * MB);
  bf16_t* q = (bf16_t*)(p + 18 * MB);     // [8][T][E]; dead after scores
  float* fin4 = (float*)(p + 18 * MB);    // [4][T][E] f32 — aliases q
  bf16_t* k = (bf16_t*)(p + 34 * MB);     // [8][T][E]
  bf16_t* vT = (bf16_t*)(p + 50 * MB);    // [8][E][T]
  bf16_t* att = (bf16_t*)(p + 66 * MB);   // [8][T][T]; dead after AV
  bf16_t* Wfb = (bf16_t*)(p + 66 * MB);   // [T][H*T] bf16 — aliases att
  bf16_t* hoT = (bf16_t*)(p + 130 * MB);  // [E][H*T]

  // input converts
  cvt_bf16<<<nTE / 2048, 256, 0, stream>>>(x, xb);
  cvt_bf16<<<nTE / 2048, 256, 0, stream>>>(y, yb);
  cvt_bf16<<<nTE / 2048, 256, 0, stream>>>(z, zb);
  cvt_bf16<<<nW / 2048, 256, 0, stream>>>(Wq, Wqb);
  cvt_bf16<<<nW / 2048, 256, 0, stream>>>(Wk, Wkb);
  cvt_bf16<<<nW / 2048, 256, 0, stream>>>(Wv, Wvb);

  // q[h] = x Wq[h]^T + bq[h] ; k likewise
  mfma_gemm_nt<bf16_t><<<dim3(16, 4, 8), 256, 0, stream>>>(
      xb, Wqb, q, nullptr, bq, EE, EE, EE, EE, 0, (int64_t)EE * EE, (int64_t)TT * EE, 0, EE);
  mfma_gemm_nt<bf16_t><<<dim3(16, 4, 8), 256, 0, stream>>>(
      yb, Wkb, k, nullptr, bk, EE, EE, EE, EE, 0, (int64_t)EE * EE, (int64_t)TT * EE, 0, EE);
  // vT[h][f][t] = Wv[h][f][:] . z[t][:] + bv[h][f]
  mfma_gemm_nt<bf16_t><<<dim3(4, 16, 8), 256, 0, stream>>>(
      Wvb, zb, vT, bv, nullptr, EE, EE, EE, TT, (int64_t)EE * EE, 0, (int64_t)EE * TT, EE, 0);
  // att[h][s][t] = q[h][s][:] . k[h][t][:]
  mfma_gemm_nt<bf16_t><<<dim3(16, 16, 8), 256, 0, stream>>>(
      q, k, att, nullptr, nullptr, EE, EE, EE, TT, (int64_t)TT * EE, (int64_t)TT * EE,
      (int64_t)TT * TT, 0, 0);
  softmax_rows<<<HH * TT, 256, 0, stream>>>(att);
  // hoT[f][h*T+s] = vT[h][f][:] . att[h][s][:]
  mfma_gemm_nt<bf16_t><<<dim3(4, 16, 8), 256, 0, stream>>>(
      vT, att, hoT, nullptr, nullptr, TT, TT, TT, HT, (int64_t)EE * TT, (int64_t)TT * TT,
      (int64_t)TT, 0, 0);
  // Wf -> bf16 (att is dead now; Wfb aliases it)
  cvt_bf16<<<nWf / 2048, 256, 0, stream>>>(Wf, Wfb);
  // fin4[zk][t][e] = sum_{k in slice zk} Wfb[t][k] * hoT[e][k]  (split-K=4, no atomics)
  mfma_gemm_nt<float><<<dim3(16, 4, 4), 256, 0, stream>>>(
      Wfb, hoT, fin4, nullptr, nullptr, 4096, HT, HT, EE, 4096, 4096, (int64_t)TT * EE, 0, 0);
  // out = LN(sum fin4 + bf + z)
  ln_res4<<<TT, 256, 0, stream>>>(fin4, z, bfb, out);
}